// Round 14
// baseline (99.657 us; speedup 1.0000x reference)
//
#include <hip/hip_runtime.h>
#include <hip/hip_bf16.h>
#include <stdint.h>

#define B_    4
#define H_    16
#define L_    2048
#define D_    64
#define BH_   64
#define NT_   32
#define MASKBIAS (-1.4426950408889634e9f)   // -1e9 * log2(e), exp2-domain

typedef __attribute__((ext_vector_type(8))) short bf16x8;
typedef __attribute__((ext_vector_type(8))) unsigned short ushort8;
typedef __attribute__((ext_vector_type(4))) unsigned short ushort4v;
typedef __attribute__((ext_vector_type(4))) float f32x4;
typedef __attribute__((ext_vector_type(16))) float f32x16;

__device__ __forceinline__ ushort f2bf(float f) {
  union { float f; uint32_t u; } x; x.f = f;
  uint32_t r = x.u + 0x7FFFu + ((x.u >> 16) & 1u);
  return (ushort)(r >> 16);
}

__device__ __forceinline__ uint32_t pkbf(float lo, float hi) {
  uint32_t r;
  asm("v_cvt_pk_bf16_f32 %0, %1, %2" : "=v"(r) : "v"(lo), "v"(hi));
  return r;
}

// ---------------- pre-pass: fp32 -> bf16 + mask bias ----------------
// Kp tile (bh,kt): elem(row,d) at row*64 + (d ^ ((row&7)<<3))          [unchanged]
// Vtp tile (for 32x32 PV): elem at ((h*2+c)*64 + d)*16 + s, s=hi*8+e,
//   holding V[k][d] with k = (e&3) + 4*hi + 8*(e>>2) + 16*c + 32*h
// Mb[b][k] = 0.0f (keep) or MASKBIAS (drop)
__global__ __launch_bounds__(256, 2)
void prep_kv(const float* __restrict__ K, const float* __restrict__ V,
             const int* __restrict__ Mask,
             ushort* __restrict__ Kp, ushort* __restrict__ Vtp,
             float* __restrict__ Mb)
{
  __shared__ ushort Vl[64 * 68];
  const int bid = blockIdx.x;      // bh*32 + kt
  const int tid = threadIdx.x;
  const float* Kg = K + (size_t)bid * 4096;
  const float* Vg = V + (size_t)bid * 4096;
  ushort* Kt = Kp + (size_t)bid * 4096;
  ushort* Vt = Vtp + (size_t)bid * 4096;

#pragma unroll
  for (int j = 0; j < 2; ++j) {
    int chunk = j * 256 + tid;
    int row = chunk >> 3, d8 = chunk & 7;
    const float* s = Kg + row * 64 + d8 * 8;
    float4 a = *(const float4*)s, b2 = *(const float4*)(s + 4);
    ushort8 o;
    o[0]=f2bf(a.x); o[1]=f2bf(a.y); o[2]=f2bf(a.z); o[3]=f2bf(a.w);
    o[4]=f2bf(b2.x);o[5]=f2bf(b2.y);o[6]=f2bf(b2.z);o[7]=f2bf(b2.w);
    *(ushort8*)(Kt + row * 64 + ((d8 * 8) ^ ((row & 7) << 3))) = o;

    const float* sv = Vg + row * 64 + d8 * 8;
    float4 va = *(const float4*)sv, vb2 = *(const float4*)(sv + 4);
    ushort4v w0, w1;
    w0[0]=f2bf(va.x); w0[1]=f2bf(va.y); w0[2]=f2bf(va.z); w0[3]=f2bf(va.w);
    w1[0]=f2bf(vb2.x);w1[1]=f2bf(vb2.y);w1[2]=f2bf(vb2.z);w1[3]=f2bf(vb2.w);
    *(ushort4v*)(&Vl[row * 68 + d8 * 8])     = w0;
    *(ushort4v*)(&Vl[row * 68 + d8 * 8 + 4]) = w1;
  }
  __syncthreads();
  // V gather into 32x32-PV fragment order
#pragma unroll
  for (int j = 0; j < 2; ++j) {
    int chunk = j * 256 + tid;          // 0..511
    int sh = chunk & 1;
    int d  = (chunk >> 1) & 63;
    int c  = (chunk >> 7) & 1;
    int h  = (chunk >> 8) & 1;
    ushort8 o;
#pragma unroll
    for (int e = 0; e < 8; ++e) {
      int k = (e & 3) + 4 * sh + 8 * (e >> 2) + 16 * c + 32 * h;
      o[e] = Vl[k * 68 + d];
    }
    *(ushort8*)(Vt + ((h * 2 + c) * 64 + d) * 16 + sh * 8) = o;
  }
  if ((((bid >> 5) & 15) == 0) && tid < 64) {
    int b = bid >> 9, kt = bid & 31;
    int idx = b * 2048 + kt * 64 + tid;
    Mb[idx] = (Mask[idx] != 0) ? 0.f : MASKBIAS;
  }
}

// ------- main attention: r12 schedule, 32x32x16 MFMAs -------
__global__ __launch_bounds__(256, 2)
void attn_fwd14(const float* __restrict__ Q, const float* __restrict__ Mb,
                const ushort* __restrict__ Kp, const ushort* __restrict__ Vtp,
                float* __restrict__ O)
{
  __shared__ __align__(16) ushort Kb[2][4096];
  __shared__ __align__(16) ushort Vb[2][4096];

  const int tid  = threadIdx.x;
  const int wid  = tid >> 6;
  const int lane = tid & 63;
  const int lq   = lane & 31;          // q-col (and d-col / k-row index)
  const int hi   = lane >> 5;          // lane half

  // XCD-aware mapping: 64 contiguous logical blocks per XCD -> 8 bh per XCD
  const int x   = blockIdx.x;           // 0..511
  const int lin = (x & 7) * 64 + (x >> 3);
  const int bh  = lin >> 3;             // 0..63
  const int qt  = lin & 7;              // 0..7
  const int b   = bh >> 4;

  // de-phase the 2 co-resident dispatch rounds by 16 KV-tiles
  const int phase = ((x >> 8) & 1) << 4;

  const float*  Qg    = Q + (size_t)bh * L_ * D_;
  float*        Og    = O + (size_t)bh * L_ * D_;
  const ushort* Kbase = Kp  + (size_t)bh * 131072;
  const ushort* Vbase = Vtp + (size_t)bh * 131072;
  const float*  Mbb   = Mb + (size_t)b * L_;

  const int qbase = qt * 256 + wid * 64;
  const float qscale = 0.125f * 1.4426950408889634f;  // scale * log2(e)

  // ---- Q fragments (B-operand, 32x32): lane holds Q[qbase+g*32+lq][s*16+hi*8+e] ----
  bf16x8 qf[2][4];
#pragma unroll
  for (int g = 0; g < 2; ++g)
#pragma unroll
    for (int s = 0; s < 4; ++s) {
      const float* src = Qg + (size_t)(qbase + g * 32 + lq) * D_ + s * 16 + hi * 8;
      float4 a = *(const float4*)src, b2 = *(const float4*)(src + 4);
      bf16x8 q;
      q[0]=f2bf(a.x*qscale);  q[1]=f2bf(a.y*qscale);  q[2]=f2bf(a.z*qscale);  q[3]=f2bf(a.w*qscale);
      q[4]=f2bf(b2.x*qscale); q[5]=f2bf(b2.y*qscale); q[6]=f2bf(b2.z*qscale); q[7]=f2bf(b2.w*qscale);
      qf[g][s] = q;
    }

  f32x16 o_acc[2][2];                   // [g][dh]
#pragma unroll
  for (int g = 0; g < 2; ++g)
#pragma unroll
    for (int dh = 0; dh < 2; ++dh)
#pragma unroll
      for (int r = 0; r < 16; ++r) o_acc[g][dh][r] = 0.f;
  f32x4 l4[2];
#pragma unroll
  for (int g = 0; g < 2; ++g) l4[g] = (f32x4){0.f,0.f,0.f,0.f};

  // ---- staging prologue: tile `phase` -> regs ----
  int kts = phase;
  ushort8 rk0, rk1, rv0, rv1;
  rk0 = *(const ushort8*)(Kbase + (size_t)kts * 4096 + wid * 1024 + lane * 8);
  rk1 = *(const ushort8*)(Kbase + (size_t)kts * 4096 + wid * 1024 + 512 + lane * 8);
  rv0 = *(const ushort8*)(Vbase + (size_t)kts * 4096 + wid * 1024 + lane * 8);
  rv1 = *(const ushort8*)(Vbase + (size_t)kts * 4096 + wid * 1024 + 512 + lane * 8);

  int cur = 0;
  for (int kt = 0; kt < NT_; ++kt) {
    *(ushort8*)(&Kb[cur][wid * 1024 + lane * 8])       = rk0;
    *(ushort8*)(&Kb[cur][wid * 1024 + 512 + lane * 8]) = rk1;
    *(ushort8*)(&Vb[cur][wid * 1024 + lane * 8])       = rv0;
    *(ushort8*)(&Vb[cur][wid * 1024 + 512 + lane * 8]) = rv1;

    __syncthreads();

    const int knx = (kts + 1) & 31;
    {
      const ushort* Ks = Kbase + (size_t)knx * 4096;
      const ushort* Vs = Vbase + (size_t)knx * 4096;
      rk0 = *(const ushort8*)(Ks + wid * 1024 + lane * 8);
      rk1 = *(const ushort8*)(Ks + wid * 1024 + 512 + lane * 8);
      rv0 = *(const ushort8*)(Vs + wid * 1024 + lane * 8);
      rv1 = *(const ushort8*)(Vs + wid * 1024 + 512 + lane * 8);
    }

    // ---- bias C-init, f32x16 per k-half: reg r -> k = (r&3)+8*(r>>2)+4*hi+32*h ----
    f32x16 bt[2];
#pragma unroll
    for (int h = 0; h < 2; ++h)
#pragma unroll
      for (int rq = 0; rq < 4; ++rq) {
        f32x4 t = *(const f32x4*)(Mbb + kts * 64 + 32 * h + 8 * rq + 4 * hi);
#pragma unroll
        for (int j = 0; j < 4; ++j) bt[h][rq * 4 + j] = t[j];
      }

    const ushort* Kc = Kb[cur];
    const ushort* Vc = Vb[cur];

    // ---- K fragments (A-operand): lane holds K[lq+32h][s*16+hi*8+e], swizzled LDS ----
    bf16x8 kf[2][4];
#pragma unroll
    for (int h = 0; h < 2; ++h)
#pragma unroll
      for (int s = 0; s < 4; ++s)
        kf[h][s] = *(const bf16x8*)(Kc + (lq + 32 * h) * 64 + ((s * 16 + hi * 8) ^ ((lq & 7) << 3)));

    // ---- per group: S^T = K Q^T (C-init=bias) -> exp2 -> pack -> l ----
    union PK2 { uint32_t u[8]; bf16x8 v[2]; } pkg[2][2];   // [g][h], v[c]
#pragma unroll
    for (int g = 0; g < 2; ++g) {
      f32x16 st0 = bt[0], st1 = bt[1];
      __builtin_amdgcn_s_setprio(1);
#pragma unroll
      for (int s = 0; s < 4; ++s)
        st0 = __builtin_amdgcn_mfma_f32_32x32x16_bf16(kf[0][s], qf[g][s], st0, 0, 0, 0);
#pragma unroll
      for (int s = 0; s < 4; ++s)
        st1 = __builtin_amdgcn_mfma_f32_32x32x16_bf16(kf[1][s], qf[g][s], st1, 0, 0, 0);
      __builtin_amdgcn_s_setprio(0);

      float p0[16], p1[16];
#pragma unroll
      for (int r = 0; r < 16; ++r) {
        p0[r] = __builtin_amdgcn_exp2f(st0[r]);
        p1[r] = __builtin_amdgcn_exp2f(st1[r]);
      }
      // l partial (per-lane, q = lq): sum the 32 values
#pragma unroll
      for (int rq = 0; rq < 4; ++rq)
#pragma unroll
        for (int j = 0; j < 4; ++j)
          l4[g][j] += p0[rq * 4 + j] + p1[rq * 4 + j];
      // pack: A-frag word (c, jw) = (p[8c+2jw], p[8c+2jw+1])
#pragma unroll
      for (int c = 0; c < 2; ++c)
#pragma unroll
        for (int jw = 0; jw < 4; ++jw) {
          pkg[g][0].u[c * 4 + jw] = pkbf(p0[8 * c + 2 * jw], p0[8 * c + 2 * jw + 1]);
          pkg[g][1].u[c * 4 + jw] = pkbf(p1[8 * c + 2 * jw], p1[8 * c + 2 * jw + 1]);
        }
    }

    // ---- O += P V : 4 kc-groups x 2 dh x 2 g ----
    __builtin_amdgcn_s_setprio(1);
#pragma unroll
    for (int kc = 0; kc < 4; ++kc) {     // kc = h*2 + c
      const int h = kc >> 1, c = kc & 1;
#pragma unroll
      for (int dh = 0; dh < 2; ++dh) {
        bf16x8 vbf = *(const bf16x8*)(Vc + (kc * 64 + lq + 32 * dh) * 16 + hi * 8);
#pragma unroll
        for (int g = 0; g < 2; ++g)
          o_acc[g][dh] = __builtin_amdgcn_mfma_f32_32x32x16_bf16(pkg[g][h].v[c], vbf, o_acc[g][dh], 0, 0, 0);
      }
    }
    __builtin_amdgcn_s_setprio(0);

    kts = knx;
    cur ^= 1;
  }

  // ---- epilogue: l full-sum, per-row inverse, scaled stores ----
#pragma unroll
  for (int g = 0; g < 2; ++g) {
    float lsum = (l4[g][0] + l4[g][1]) + (l4[g][2] + l4[g][3]);
    lsum += __shfl_xor(lsum, 32);       // lane l and l+32 hold complementary k-halves
    float lv[16];
#pragma unroll
    for (int rq = 0; rq < 4; ++rq)
#pragma unroll
      for (int j = 0; j < 4; ++j) {
        int row = j + 8 * rq + 4 * hi;  // q within group
        lv[rq * 4 + j] = 1.0f / __shfl(lsum, row);
      }
#pragma unroll
    for (int dh = 0; dh < 2; ++dh)
#pragma unroll
      for (int rq = 0; rq < 4; ++rq)
#pragma unroll
        for (int j = 0; j < 4; ++j) {
          int row = j + 8 * rq + 4 * hi;
          Og[(size_t)(qbase + g * 32 + row) * D_ + dh * 32 + lq] =
              o_acc[g][dh][rq * 4 + j] * lv[rq * 4 + j];
        }
  }
}

extern "C" void kernel_launch(void* const* d_in, const int* in_sizes, int n_in,
                              void* d_out, int out_size, void* d_ws, size_t ws_size,
                              hipStream_t stream) {
  const float* Q = (const float*)d_in[0];
  const float* K = (const float*)d_in[1];
  const float* V = (const float*)d_in[2];
  const int*   M = (const int*)d_in[3];
  float*       O = (float*)d_out;

  const size_t elems = (size_t)BH_ * L_ * D_;   // 8,388,608
  ushort* Kp  = (ushort*)d_ws;
  ushort* Vtp = Kp + elems;
  float*  Mb  = (float*)(Vtp + elems);          // 4*2048 floats
  prep_kv<<<dim3(BH_ * NT_), dim3(256), 0, stream>>>(K, V, M, Kp, Vtp, Mb);
  attn_fwd14<<<dim3(512), dim3(256), 0, stream>>>(Q, Mb, Kp, Vtp, O);
}

// Round 15
// 99.237 us; speedup vs baseline: 1.0042x; 1.0042x over previous
//
#include <hip/hip_runtime.h>
#include <hip/hip_bf16.h>
#include <stdint.h>

#define B_    4
#define H_    16
#define L_    2048
#define D_    64
#define BH_   64
#define NT_   32
#define MASKBIAS (-1.4426950408889634e9f)   // -1e9 * log2(e), exp2-domain

typedef __attribute__((ext_vector_type(8))) short bf16x8;
typedef __attribute__((ext_vector_type(8))) unsigned short ushort8;
typedef __attribute__((ext_vector_type(4))) unsigned short ushort4v;
typedef __attribute__((ext_vector_type(4))) float f32x4;
typedef __attribute__((ext_vector_type(16))) float f32x16;

__device__ __forceinline__ ushort f2bf(float f) {
  union { float f; uint32_t u; } x; x.f = f;
  uint32_t r = x.u + 0x7FFFu + ((x.u >> 16) & 1u);
  return (ushort)(r >> 16);
}

__device__ __forceinline__ uint32_t pkbf(float lo, float hi) {
  uint32_t r;
  asm("v_cvt_pk_bf16_f32 %0, %1, %2" : "=v"(r) : "v"(lo), "v"(hi));
  return r;
}

// ---------------- pre-pass: fp32 -> bf16 + mask bias ----------------
// Kp tile (bh,kt): elem(row,d) at row*64 + (d ^ ((row&7)<<3))       [128B rows, swizzled]
// Vtp tile (32x32 PV, 128B rows): row d (64 ushorts), col = kc*16 + sh*8 + e,
//   swizzled (col8 = kc*2+sh): store at d*64 + ((col8*8) ^ ((d&7)<<3)) + e,
//   holding V[k][d] with k = (e&3) + 4*sh + 8*(e>>2) + 16*c + 32*h, kc = h*2+c
// Mb[b][k] = 0.0f (keep) or MASKBIAS (drop)
__global__ __launch_bounds__(256, 2)
void prep_kv(const float* __restrict__ K, const float* __restrict__ V,
             const int* __restrict__ Mask,
             ushort* __restrict__ Kp, ushort* __restrict__ Vtp,
             float* __restrict__ Mb)
{
  __shared__ ushort Vl[64 * 68];
  const int bid = blockIdx.x;      // bh*32 + kt
  const int tid = threadIdx.x;
  const float* Kg = K + (size_t)bid * 4096;
  const float* Vg = V + (size_t)bid * 4096;
  ushort* Kt = Kp + (size_t)bid * 4096;
  ushort* Vt = Vtp + (size_t)bid * 4096;

#pragma unroll
  for (int j = 0; j < 2; ++j) {
    int chunk = j * 256 + tid;
    int row = chunk >> 3, d8 = chunk & 7;
    const float* s = Kg + row * 64 + d8 * 8;
    float4 a = *(const float4*)s, b2 = *(const float4*)(s + 4);
    ushort8 o;
    o[0]=f2bf(a.x); o[1]=f2bf(a.y); o[2]=f2bf(a.z); o[3]=f2bf(a.w);
    o[4]=f2bf(b2.x);o[5]=f2bf(b2.y);o[6]=f2bf(b2.z);o[7]=f2bf(b2.w);
    *(ushort8*)(Kt + row * 64 + ((d8 * 8) ^ ((row & 7) << 3))) = o;

    const float* sv = Vg + row * 64 + d8 * 8;
    float4 va = *(const float4*)sv, vb2 = *(const float4*)(sv + 4);
    ushort4v w0, w1;
    w0[0]=f2bf(va.x); w0[1]=f2bf(va.y); w0[2]=f2bf(va.z); w0[3]=f2bf(va.w);
    w1[0]=f2bf(vb2.x);w1[1]=f2bf(vb2.y);w1[2]=f2bf(vb2.z);w1[3]=f2bf(vb2.w);
    *(ushort4v*)(&Vl[row * 68 + d8 * 8])     = w0;
    *(ushort4v*)(&Vl[row * 68 + d8 * 8 + 4]) = w1;
  }
  __syncthreads();
  // V gather into 32x32-PV fragment order, 128B rows (d-major) with K-style swizzle
#pragma unroll
  for (int j = 0; j < 2; ++j) {
    int chunk = j * 256 + tid;          // 0..511
    int d    = chunk >> 3;              // 0..63
    int col8 = chunk & 7;               // 0..7  (= kc*2 + sh)
    int kc   = col8 >> 1;
    int sh   = col8 & 1;
    int c    = kc & 1;
    int h    = kc >> 1;
    ushort8 o;
#pragma unroll
    for (int e = 0; e < 8; ++e) {
      int k = (e & 3) + 4 * sh + 8 * (e >> 2) + 16 * c + 32 * h;
      o[e] = Vl[k * 68 + d];
    }
    *(ushort8*)(Vt + d * 64 + ((col8 * 8) ^ ((d & 7) << 3))) = o;
  }
  if ((((bid >> 5) & 15) == 0) && tid < 64) {
    int b = bid >> 9, kt = bid & 31;
    int idx = b * 2048 + kt * 64 + tid;
    Mb[idx] = (Mask[idx] != 0) ? 0.f : MASKBIAS;
  }
}

// ------- main attention: r12 schedule, 32x32x16 MFMAs, conflict-free V rows -------
__global__ __launch_bounds__(256, 2)
void attn_fwd15(const float* __restrict__ Q, const float* __restrict__ Mb,
                const ushort* __restrict__ Kp, const ushort* __restrict__ Vtp,
                float* __restrict__ O)
{
  __shared__ __align__(16) ushort Kb[2][4096];
  __shared__ __align__(16) ushort Vb[2][4096];

  const int tid  = threadIdx.x;
  const int wid  = tid >> 6;
  const int lane = tid & 63;
  const int lq   = lane & 31;          // q-col / d-col / k-row index
  const int hi   = lane >> 5;          // lane half

  // XCD-aware mapping: 64 contiguous logical blocks per XCD -> 8 bh per XCD
  const int x   = blockIdx.x;           // 0..511
  const int lin = (x & 7) * 64 + (x >> 3);
  const int bh  = lin >> 3;             // 0..63
  const int qt  = lin & 7;              // 0..7
  const int b   = bh >> 4;

  // de-phase the 2 co-resident dispatch rounds by 16 KV-tiles
  const int phase = ((x >> 8) & 1) << 4;

  const float*  Qg    = Q + (size_t)bh * L_ * D_;
  float*        Og    = O + (size_t)bh * L_ * D_;
  const ushort* Kbase = Kp  + (size_t)bh * 131072;
  const ushort* Vbase = Vtp + (size_t)bh * 131072;
  const float*  Mbb   = Mb + (size_t)b * L_;

  const int qbase = qt * 256 + wid * 64;
  const float qscale = 0.125f * 1.4426950408889634f;  // scale * log2(e)

  // ---- Q fragments (B-operand, 32x32): lane holds Q[qbase+g*32+lq][s*16+hi*8+e] ----
  bf16x8 qf[2][4];
#pragma unroll
  for (int g = 0; g < 2; ++g)
#pragma unroll
    for (int s = 0; s < 4; ++s) {
      const float* src = Qg + (size_t)(qbase + g * 32 + lq) * D_ + s * 16 + hi * 8;
      float4 a = *(const float4*)src, b2 = *(const float4*)(src + 4);
      bf16x8 q;
      q[0]=f2bf(a.x*qscale);  q[1]=f2bf(a.y*qscale);  q[2]=f2bf(a.z*qscale);  q[3]=f2bf(a.w*qscale);
      q[4]=f2bf(b2.x*qscale); q[5]=f2bf(b2.y*qscale); q[6]=f2bf(b2.z*qscale); q[7]=f2bf(b2.w*qscale);
      qf[g][s] = q;
    }

  f32x16 o_acc[2][2];                   // [g][dh]
#pragma unroll
  for (int g = 0; g < 2; ++g)
#pragma unroll
    for (int dh = 0; dh < 2; ++dh)
#pragma unroll
      for (int r = 0; r < 16; ++r) o_acc[g][dh][r] = 0.f;
  f32x4 l4[2];
#pragma unroll
  for (int g = 0; g < 2; ++g) l4[g] = (f32x4){0.f,0.f,0.f,0.f};

  // ---- staging prologue: tile `phase` -> regs ----
  int kts = phase;
  ushort8 rk0, rk1, rv0, rv1;
  rk0 = *(const ushort8*)(Kbase + (size_t)kts * 4096 + wid * 1024 + lane * 8);
  rk1 = *(const ushort8*)(Kbase + (size_t)kts * 4096 + wid * 1024 + 512 + lane * 8);
  rv0 = *(const ushort8*)(Vbase + (size_t)kts * 4096 + wid * 1024 + lane * 8);
  rv1 = *(const ushort8*)(Vbase + (size_t)kts * 4096 + wid * 1024 + 512 + lane * 8);

  int cur = 0;
  for (int kt = 0; kt < NT_; ++kt) {
    *(ushort8*)(&Kb[cur][wid * 1024 + lane * 8])       = rk0;
    *(ushort8*)(&Kb[cur][wid * 1024 + 512 + lane * 8]) = rk1;
    *(ushort8*)(&Vb[cur][wid * 1024 + lane * 8])       = rv0;
    *(ushort8*)(&Vb[cur][wid * 1024 + 512 + lane * 8]) = rv1;

    __syncthreads();

    const int knx = (kts + 1) & 31;
    {
      const ushort* Ks = Kbase + (size_t)knx * 4096;
      const ushort* Vs = Vbase + (size_t)knx * 4096;
      rk0 = *(const ushort8*)(Ks + wid * 1024 + lane * 8);
      rk1 = *(const ushort8*)(Ks + wid * 1024 + 512 + lane * 8);
      rv0 = *(const ushort8*)(Vs + wid * 1024 + lane * 8);
      rv1 = *(const ushort8*)(Vs + wid * 1024 + 512 + lane * 8);
    }

    // ---- bias C-init, f32x16 per k-half: reg r -> k = (r&3)+8*(r>>2)+4*hi (+32h) ----
    f32x16 bt[2];
#pragma unroll
    for (int h = 0; h < 2; ++h)
#pragma unroll
      for (int rq = 0; rq < 4; ++rq) {
        f32x4 t = *(const f32x4*)(Mbb + kts * 64 + 32 * h + 8 * rq + 4 * hi);
#pragma unroll
        for (int j = 0; j < 4; ++j) bt[h][rq * 4 + j] = t[j];
      }

    const ushort* Kc = Kb[cur];
    const ushort* Vc = Vb[cur];

    // ---- K fragments (A-operand): lane holds K[lq+32h][s*16+hi*8+e], swizzled ----
    bf16x8 kf[2][4];
#pragma unroll
    for (int h = 0; h < 2; ++h)
#pragma unroll
      for (int s = 0; s < 4; ++s)
        kf[h][s] = *(const bf16x8*)(Kc + (lq + 32 * h) * 64 + ((s * 16 + hi * 8) ^ ((lq & 7) << 3)));

    // ---- per group: S^T = K Q^T (C-init=bias) -> exp2 -> pack -> l ----
    union PK2 { uint32_t u[8]; bf16x8 v[2]; } pkg[2][2];   // [g][h], v[c]
#pragma unroll
    for (int g = 0; g < 2; ++g) {
      f32x16 st0 = bt[0], st1 = bt[1];
      __builtin_amdgcn_s_setprio(1);
#pragma unroll
      for (int s = 0; s < 4; ++s)
        st0 = __builtin_amdgcn_mfma_f32_32x32x16_bf16(kf[0][s], qf[g][s], st0, 0, 0, 0);
#pragma unroll
      for (int s = 0; s < 4; ++s)
        st1 = __builtin_amdgcn_mfma_f32_32x32x16_bf16(kf[1][s], qf[g][s], st1, 0, 0, 0);
      __builtin_amdgcn_s_setprio(0);

      float p0[16], p1[16];
#pragma unroll
      for (int r = 0; r < 16; ++r) {
        p0[r] = __builtin_amdgcn_exp2f(st0[r]);
        p1[r] = __builtin_amdgcn_exp2f(st1[r]);
      }
#pragma unroll
      for (int rq = 0; rq < 4; ++rq)
#pragma unroll
        for (int j = 0; j < 4; ++j)
          l4[g][j] += p0[rq * 4 + j] + p1[rq * 4 + j];
#pragma unroll
      for (int c = 0; c < 2; ++c)
#pragma unroll
        for (int jw = 0; jw < 4; ++jw) {
          pkg[g][0].u[c * 4 + jw] = pkbf(p0[8 * c + 2 * jw], p0[8 * c + 2 * jw + 1]);
          pkg[g][1].u[c * 4 + jw] = pkbf(p1[8 * c + 2 * jw], p1[8 * c + 2 * jw + 1]);
        }
    }

    // ---- O += P V : V rows 128B + swizzle (K-read shape, conflict-free) ----
    __builtin_amdgcn_s_setprio(1);
#pragma unroll
    for (int kc = 0; kc < 4; ++kc) {     // kc = h*2 + c
      const int h = kc >> 1, c = kc & 1;
#pragma unroll
      for (int dh = 0; dh < 2; ++dh) {
        const int d = lq + 32 * dh;
        bf16x8 vbf = *(const bf16x8*)(Vc + d * 64 + (((kc * 2 + hi) * 8) ^ ((d & 7) << 3)));
#pragma unroll
        for (int g = 0; g < 2; ++g)
          o_acc[g][dh] = __builtin_amdgcn_mfma_f32_32x32x16_bf16(pkg[g][h].v[c], vbf, o_acc[g][dh], 0, 0, 0);
      }
    }
    __builtin_amdgcn_s_setprio(0);

    kts = knx;
    cur ^= 1;
  }

  // ---- epilogue: l full-sum, per-row inverse, scaled stores ----
#pragma unroll
  for (int g = 0; g < 2; ++g) {
    float lsum = (l4[g][0] + l4[g][1]) + (l4[g][2] + l4[g][3]);
    lsum += __shfl_xor(lsum, 32);       // lanes l and l+32 hold complementary k-halves
    float lv[16];
#pragma unroll
    for (int rq = 0; rq < 4; ++rq)
#pragma unroll
      for (int j = 0; j < 4; ++j) {
        int row = j + 8 * rq + 4 * hi;  // q within group
        lv[rq * 4 + j] = 1.0f / __shfl(lsum, row);
      }
#pragma unroll
    for (int dh = 0; dh < 2; ++dh)
#pragma unroll
      for (int rq = 0; rq < 4; ++rq)
#pragma unroll
        for (int j = 0; j < 4; ++j) {
          int row = j + 8 * rq + 4 * hi;
          Og[(size_t)(qbase + g * 32 + row) * D_ + dh * 32 + lq] =
              o_acc[g][dh][rq * 4 + j] * lv[rq * 4 + j];
        }
  }
}

extern "C" void kernel_launch(void* const* d_in, const int* in_sizes, int n_in,
                              void* d_out, int out_size, void* d_ws, size_t ws_size,
                              hipStream_t stream) {
  const float* Q = (const float*)d_in[0];
  const float* K = (const float*)d_in[1];
  const float* V = (const float*)d_in[2];
  const int*   M = (const int*)d_in[3];
  float*       O = (float*)d_out;

  const size_t elems = (size_t)BH_ * L_ * D_;   // 8,388,608
  ushort* Kp  = (ushort*)d_ws;
  ushort* Vtp = Kp + elems;
  float*  Mb  = (float*)(Vtp + elems);          // 4*2048 floats
  prep_kv<<<dim3(BH_ * NT_), dim3(256), 0, stream>>>(K, V, M, Kp, Vtp, Mb);
  attn_fwd15<<<dim3(512), dim3(256), 0, stream>>>(Q, Mb, Kp, Vtp, O);
}

// Round 16
// 87.386 us; speedup vs baseline: 1.1404x; 1.1356x over previous
//
#include <hip/hip_runtime.h>
#include <hip/hip_bf16.h>
#include <stdint.h>

#define B_    4
#define H_    16
#define L_    2048
#define D_    64
#define BH_   64
#define NT_   32
#define MASKBIAS (-1.4426950408889634e9f)   // -1e9 * log2(e), exp2-domain

typedef __attribute__((ext_vector_type(8))) short bf16x8;
typedef __attribute__((ext_vector_type(8))) unsigned short ushort8;
typedef __attribute__((ext_vector_type(4))) unsigned short ushort4v;
typedef __attribute__((ext_vector_type(4))) float f32x4;

__device__ __forceinline__ ushort f2bf(float f) {
  union { float f; uint32_t u; } x; x.f = f;
  uint32_t r = x.u + 0x7FFFu + ((x.u >> 16) & 1u);
  return (ushort)(r >> 16);
}

__device__ __forceinline__ uint32_t pkbf(float lo, float hi) {
  uint32_t r;
  asm("v_cvt_pk_bf16_f32 %0, %1, %2" : "=v"(r) : "v"(lo), "v"(hi));
  return r;
}

// ---------------- pre-pass: fp32 -> bf16, tiled + permuted + swizzled + mask bias ----------------
// Kp tile (bh,kt): elem(row,d) at row*64 + (d ^ ((row&7)<<3))
// Vtp tile: elem(d,pos) at d*64 + (pos ^ ((d&7)<<3)), holding V[k(pos)][d],
//   pos = 32c+8lg+4b+a  <->  k = 32c+16b+4lg+a  (MFMA A-frag slot order)
// Mb[b][k] = 0.0f (keep) or MASKBIAS (drop)
__global__ __launch_bounds__(256, 2)
void prep_kv(const float* __restrict__ K, const float* __restrict__ V,
             const int* __restrict__ Mask,
             ushort* __restrict__ Kp, ushort* __restrict__ Vtp,
             float* __restrict__ Mb)
{
  __shared__ ushort Vl[64 * 68];
  const int bid = blockIdx.x;      // bh*32 + kt
  const int tid = threadIdx.x;
  const float* Kg = K + (size_t)bid * 4096;
  const float* Vg = V + (size_t)bid * 4096;
  ushort* Kt = Kp + (size_t)bid * 4096;
  ushort* Vt = Vtp + (size_t)bid * 4096;

#pragma unroll
  for (int j = 0; j < 2; ++j) {
    int chunk = j * 256 + tid;
    int row = chunk >> 3, d8 = chunk & 7;
    const float* s = Kg + row * 64 + d8 * 8;
    float4 a = *(const float4*)s, b2 = *(const float4*)(s + 4);
    ushort8 o;
    o[0]=f2bf(a.x); o[1]=f2bf(a.y); o[2]=f2bf(a.z); o[3]=f2bf(a.w);
    o[4]=f2bf(b2.x);o[5]=f2bf(b2.y);o[6]=f2bf(b2.z);o[7]=f2bf(b2.w);
    *(ushort8*)(Kt + row * 64 + ((d8 * 8) ^ ((row & 7) << 3))) = o;

    const float* sv = Vg + row * 64 + d8 * 8;
    float4 va = *(const float4*)sv, vb2 = *(const float4*)(sv + 4);
    ushort4v w0, w1;
    w0[0]=f2bf(va.x); w0[1]=f2bf(va.y); w0[2]=f2bf(va.z); w0[3]=f2bf(va.w);
    w1[0]=f2bf(vb2.x);w1[1]=f2bf(vb2.y);w1[2]=f2bf(vb2.z);w1[3]=f2bf(vb2.w);
    *(ushort4v*)(&Vl[row * 68 + d8 * 8])     = w0;
    *(ushort4v*)(&Vl[row * 68 + d8 * 8 + 4]) = w1;
  }
  __syncthreads();
#pragma unroll
  for (int j = 0; j < 2; ++j) {
    int chunk = j * 256 + tid;
    int d = chunk >> 3, p8 = chunk & 7;
    ushort8 o;
#pragma unroll
    for (int e = 0; e < 8; ++e) {
      int pos = p8 * 8 + e;
      int c = pos >> 5, lgv = (pos >> 3) & 3, bb = (pos >> 2) & 1, aa = pos & 3;
      int kk = 32 * c + 16 * bb + 4 * lgv + aa;
      o[e] = Vl[kk * 68 + d];
    }
    *(ushort8*)(Vt + d * 64 + ((p8 * 8) ^ ((d & 7) << 3))) = o;
  }
  if ((((bid >> 5) & 15) == 0) && tid < 64) {
    int b = bid >> 9, kt = bid & 31;
    int idx = b * 2048 + kt * 64 + tid;
    Mb[idx] = (Mask[idx] != 0) ? 0.f : MASKBIAS;
  }
}

// ------- main attention: r12 geometry + PV rotated one iteration (reg-resident) -------
__global__ __launch_bounds__(256, 2)
void attn_fwd16(const float* __restrict__ Q, const float* __restrict__ Mb,
                const ushort* __restrict__ Kp, const ushort* __restrict__ Vtp,
                float* __restrict__ O)
{
  __shared__ __align__(16) ushort Kb[2][4096];
  __shared__ __align__(16) ushort Vb[2][4096];

  const int tid  = threadIdx.x;
  const int wid  = tid >> 6;
  const int lane = tid & 63;
  const int lr   = lane & 15;
  const int lg   = lane >> 4;

  // XCD-aware mapping: 64 contiguous logical blocks per XCD -> 8 bh per XCD
  const int x   = blockIdx.x;           // 0..511
  const int lin = (x & 7) * 64 + (x >> 3);
  const int bh  = lin >> 3;             // 0..63
  const int qt  = lin & 7;              // 0..7
  const int b   = bh >> 4;

  // de-phase the 2 co-resident dispatch rounds by 16 KV-tiles
  const int phase = ((x >> 8) & 1) << 4;

  const float*  Qg    = Q + (size_t)bh * L_ * D_;
  float*        Og    = O + (size_t)bh * L_ * D_;
  const ushort* Kbase = Kp  + (size_t)bh * 131072;
  const ushort* Vbase = Vtp + (size_t)bh * 131072;
  const float*  Mbb   = Mb + (size_t)b * L_;

  const int qbase = qt * 256 + wid * 64;
  const float qscale = 0.125f * 1.4426950408889634f;  // scale * log2(e)

  // ---- Q fragments (scaled, bf16, persistent): 4 row-groups ----
  bf16x8 qf[4][2];
#pragma unroll
  for (int g = 0; g < 4; ++g)
#pragma unroll
    for (int c = 0; c < 2; ++c) {
      const float* src = Qg + (size_t)(qbase + g * 16 + lr) * D_ + c * 32 + lg * 8;
      float4 a = *(const float4*)src, b2 = *(const float4*)(src + 4);
      bf16x8 q;
      q[0]=f2bf(a.x*qscale);  q[1]=f2bf(a.y*qscale);  q[2]=f2bf(a.z*qscale);  q[3]=f2bf(a.w*qscale);
      q[4]=f2bf(b2.x*qscale); q[5]=f2bf(b2.y*qscale); q[6]=f2bf(b2.z*qscale); q[7]=f2bf(b2.w*qscale);
      qf[g][c] = q;
    }

  f32x4 o_acc[4][4];
#pragma unroll
  for (int g = 0; g < 4; ++g)
#pragma unroll
    for (int dt = 0; dt < 4; ++dt) o_acc[g][dt] = (f32x4){0.f,0.f,0.f,0.f};
  f32x4 l_mf[4];
#pragma unroll
  for (int g = 0; g < 4; ++g) l_mf[g] = (f32x4){0.f,0.f,0.f,0.f};

  bf16x8 vone;
#pragma unroll
  for (int i = 0; i < 8; ++i) vone[i] = (short)0x3F80;  // bf16 1.0

  // persistent pipeline registers: previous tile's packed P and V fragments
  union PKU { uint32_t u[8]; bf16x8 v[2]; };
  PKU    pkp[4];
  bf16x8 vbp[4][2];

  // ---- staging prologue: tile `phase` -> regs ----
  int kts = phase;
  ushort8 rk0, rk1, rv0, rv1;
  rk0 = *(const ushort8*)(Kbase + (size_t)kts * 4096 + wid * 1024 + lane * 8);
  rk1 = *(const ushort8*)(Kbase + (size_t)kts * 4096 + wid * 1024 + 512 + lane * 8);
  rv0 = *(const ushort8*)(Vbase + (size_t)kts * 4096 + wid * 1024 + lane * 8);
  rv1 = *(const ushort8*)(Vbase + (size_t)kts * 4096 + wid * 1024 + 512 + lane * 8);

  int cur = 0;
  for (int kt = 0; kt < NT_; ++kt) {
    // publish staged regs -> buf[cur]
    *(ushort8*)(&Kb[cur][wid * 1024 + lane * 8])       = rk0;
    *(ushort8*)(&Kb[cur][wid * 1024 + 512 + lane * 8]) = rk1;
    *(ushort8*)(&Vb[cur][wid * 1024 + lane * 8])       = rv0;
    *(ushort8*)(&Vb[cur][wid * 1024 + 512 + lane * 8]) = rv1;

    __syncthreads();

    // issue next tile's global loads (fly across full compute phase)
    const int knx = (kts + 1) & 31;
    {
      const ushort* Ks = Kbase + (size_t)knx * 4096;
      const ushort* Vs = Vbase + (size_t)knx * 4096;
      rk0 = *(const ushort8*)(Ks + wid * 1024 + lane * 8);
      rk1 = *(const ushort8*)(Ks + wid * 1024 + 512 + lane * 8);
      rv0 = *(const ushort8*)(Vs + wid * 1024 + lane * 8);
      rv1 = *(const ushort8*)(Vs + wid * 1024 + 512 + lane * 8);
    }

    // mask bias (global, L2-hot) — latency covered by PV(prev) below
    f32x4 bt[4];
#pragma unroll
    for (int t = 0; t < 4; ++t) bt[t] = *(const f32x4*)(Mbb + kts * 64 + 16 * t + 4 * lg);

    const ushort* Kc = Kb[cur];
    const ushort* Vc = Vb[cur];

    // K fragment ds_reads (latency covered by PV(prev))
    bf16x8 kf[4][2];
#pragma unroll
    for (int t = 0; t < 4; ++t)
#pragma unroll
      for (int c = 0; c < 2; ++c)
        kf[t][c] = *(const bf16x8*)(Kc + (16 * t + lr) * 64 + ((c * 32 + lg * 8) ^ ((lr & 7) << 3)));

    // ---- PV + l of PREVIOUS tile: all operands in registers ----
    if (kt > 0) {
      __builtin_amdgcn_s_setprio(1);
#pragma unroll
      for (int g = 0; g < 4; ++g) {
        l_mf[g] = __builtin_amdgcn_mfma_f32_16x16x32_bf16(pkp[g].v[0], vone, l_mf[g], 0, 0, 0);
        l_mf[g] = __builtin_amdgcn_mfma_f32_16x16x32_bf16(pkp[g].v[1], vone, l_mf[g], 0, 0, 0);
      }
#pragma unroll
      for (int c = 0; c < 2; ++c)
#pragma unroll
        for (int dt = 0; dt < 4; ++dt)
#pragma unroll
          for (int g = 0; g < 4; ++g)
            o_acc[g][dt] = __builtin_amdgcn_mfma_f32_16x16x32_bf16(pkp[g].v[c], vbp[dt][c], o_acc[g][dt], 0, 0, 0);
      __builtin_amdgcn_s_setprio(0);
    }

    // V fragment ds_reads for THIS tile -> vbp (consumed next iter; huge slack)
#pragma unroll
    for (int dt = 0; dt < 4; ++dt)
#pragma unroll
      for (int c = 0; c < 2; ++c)
        vbp[dt][c] = *(const bf16x8*)(Vc + (16 * dt + lr) * 64 + ((c * 32 + lg * 8) ^ ((lr & 7) << 3)));

    // ---- QK^T (C-init=bias) -> exp2 -> pack into pkp (pkp free after PV above) ----
#pragma unroll
    for (int g = 0; g < 4; ++g) {
      f32x4 st[4];
      __builtin_amdgcn_s_setprio(1);
#pragma unroll
      for (int t = 0; t < 4; ++t)
        st[t] = __builtin_amdgcn_mfma_f32_16x16x32_bf16(kf[t][0], qf[g][0], bt[t], 0, 0, 0);
#pragma unroll
      for (int t = 0; t < 4; ++t)
        st[t] = __builtin_amdgcn_mfma_f32_16x16x32_bf16(kf[t][1], qf[g][1], st[t], 0, 0, 0);
      __builtin_amdgcn_s_setprio(0);

      f32x4 p0, p1, p2, p3;
#pragma unroll
      for (int r = 0; r < 4; ++r) {
        p0[r] = __builtin_amdgcn_exp2f(st[0][r]);
        p1[r] = __builtin_amdgcn_exp2f(st[1][r]);
        p2[r] = __builtin_amdgcn_exp2f(st[2][r]);
        p3[r] = __builtin_amdgcn_exp2f(st[3][r]);
      }
      pkp[g].u[0] = pkbf(p0[0], p0[1]); pkp[g].u[1] = pkbf(p0[2], p0[3]);
      pkp[g].u[2] = pkbf(p1[0], p1[1]); pkp[g].u[3] = pkbf(p1[2], p1[3]);
      pkp[g].u[4] = pkbf(p2[0], p2[1]); pkp[g].u[5] = pkbf(p2[2], p2[3]);
      pkp[g].u[6] = pkbf(p3[0], p3[1]); pkp[g].u[7] = pkbf(p3[2], p3[3]);
    }

    kts = knx;
    cur ^= 1;
  }

  // ---- final PV + l for the last tile ----
  __builtin_amdgcn_s_setprio(1);
#pragma unroll
  for (int g = 0; g < 4; ++g) {
    l_mf[g] = __builtin_amdgcn_mfma_f32_16x16x32_bf16(pkp[g].v[0], vone, l_mf[g], 0, 0, 0);
    l_mf[g] = __builtin_amdgcn_mfma_f32_16x16x32_bf16(pkp[g].v[1], vone, l_mf[g], 0, 0, 0);
  }
#pragma unroll
  for (int c = 0; c < 2; ++c)
#pragma unroll
    for (int dt = 0; dt < 4; ++dt)
#pragma unroll
      for (int g = 0; g < 4; ++g)
        o_acc[g][dt] = __builtin_amdgcn_mfma_f32_16x16x32_bf16(pkp[g].v[c], vbp[dt][c], o_acc[g][dt], 0, 0, 0);
  __builtin_amdgcn_s_setprio(0);

  // ---- epilogue: l_mf[g][r] already per-q (lane-replicated) ----
#pragma unroll
  for (int g = 0; g < 4; ++g) {
    float linv[4];
#pragma unroll
    for (int r = 0; r < 4; ++r) linv[r] = 1.0f / l_mf[g][r];
#pragma unroll
    for (int dt = 0; dt < 4; ++dt)
#pragma unroll
      for (int r = 0; r < 4; ++r) {
        int row = qbase + g * 16 + 4 * lg + r;
        Og[(size_t)row * D_ + dt * 16 + lr] = o_acc[g][dt][r] * linv[r];
      }
  }
}

extern "C" void kernel_launch(void* const* d_in, const int* in_sizes, int n_in,
                              void* d_out, int out_size, void* d_ws, size_t ws_size,
                              hipStream_t stream) {
  const float* Q = (const float*)d_in[0];
  const float* K = (const float*)d_in[1];
  const float* V = (const float*)d_in[2];
  const int*   M = (const int*)d_in[3];
  float*       O = (float*)d_out;

  const size_t elems = (size_t)BH_ * L_ * D_;   // 8,388,608
  ushort* Kp  = (ushort*)d_ws;
  ushort* Vtp = Kp + elems;
  float*  Mb  = (float*)(Vtp + elems);          // 4*2048 floats
  prep_kv<<<dim3(BH_ * NT_), dim3(256), 0, stream>>>(K, V, M, Kp, Vtp, Mb);
  attn_fwd16<<<dim3(512), dim3(256), 0, stream>>>(Q, Mb, Kp, Vtp, O);
}